// Round 2
// baseline (886.714 us; speedup 1.0000x reference)
//
#include <hip/hip_runtime.h>
#include <math.h>

#define NB 512
#define NI 8192
#define NLOG2 0.69314718055994530942f

__device__ __forceinline__ float log1mexp_f(float x) {
    // log(1 - exp(x)) for x <= 0, matching reference branch structure (precise ocml)
    return (x > -NLOG2) ? logf(-expm1f(x)) : log1pf(-expf(x));
}

// ---------------- Kernel 1: parallel prep: lp, lq per item (precise, unchanged) -------
__global__ __launch_bounds__(256) void prep_kernel(const float* __restrict__ logits,
                                                   float* __restrict__ Alp,   // -> ws (later x1)
                                                   float* __restrict__ Blq) { // -> d_out (later S1, then output)
    int idx = blockIdx.x * blockDim.x + threadIdx.x;  // float4 group index
    float4 x4 = ((const float4*)logits)[idx];
    float4 lp4, lq4;
    const float* xs = &x4.x;
    float* lps = &lp4.x;
    float* lqs = &lq4.x;
#pragma unroll
    for (int j = 0; j < 4; ++j) {
        float x = xs[j];
        float lp = -(fmaxf(-x, 0.0f) + log1pf(expf(-fabsf(x))));
        lp = fminf(lp, -1e-7f);
        lps[j] = lp;
        lqs[j] = log1mexp_f(lp);
    }
    ((float4*)Alp)[idx] = lp4;
    ((float4*)Blq)[idx] = lq4;
}

// ---------------- Kernel 2: sequential per-row scan ----------------
// Latency-bound dependent chain (105 cy/step measured with 1 row/lane). Now: 2 rows
// per lane (512 rows on 256 lanes, 4 blocks), interleaving two independent chains so
// the wave issues chain B while chain A waits on exp2/log2. Per-row fp op sequence is
// bit-identical to the verified kernel: only scheduling changes.
// CH=16 keeps total per-thread array footprint at 256 floats (same as the measured
// 84-VGPR 1-row kernel) to stay clear of the 512-VGPR wave limit.
#define CH 16
__device__ __forceinline__ void scan_step(float lp, float lq, float& S0, float& S1,
                                          float& x1o, float& s1o) {
    const float L2E = 1.44269504088896340736f;   // log2(e)
    const float LN2 = 0.69314718055994530942f;   // ln(2)
    float x1 = S0 + lp;
    float x2 = S1 + lq;
    float d  = x1 - x2;                          // Sterbenz-exact region; never NaN (x1 finite)
    float m  = fmaxf(x1, x2);
    float z  = fabsf(d) * -L2E;                  // single VOP3 mul w/ -abs modifier
    float e  = __builtin_amdgcn_exp2f(z);        // v_exp_f32; exp2(-inf)=0 handles S1=-inf start
    float a  = 1.0f + e;
    float l  = __builtin_amdgcn_logf(a);         // v_log_f32 = log2
    S1 = fmaf(l, LN2, m);                        // m + softplus(-|d|), single rounding
    S0 = S0 + lq;
    x1o = x1;
    s1o = S1;
}

__global__ __launch_bounds__(64, 1) void scan_kernel(float* __restrict__ A,
                                                     float* __restrict__ B) {
    int lane = blockIdx.x * blockDim.x + threadIdx.x;  // 0..255
    float* Ar0 = A + (size_t)lane * NI;
    float* Br0 = B + (size_t)lane * NI;
    float* Ar1 = A + (size_t)(lane + 256) * NI;
    float* Br1 = B + (size_t)(lane + 256) * NI;

    float S0a = 0.0f, S1a = -INFINITY;
    float S0b = 0.0f, S1b = -INFINITY;

    float lpA0[CH], lqA0[CH], lpB0[CH], lqB0[CH];
    float lpA1[CH], lqA1[CH], lpB1[CH], lqB1[CH];
    float x1A0[CH], s1A0[CH], x1B0[CH], s1B0[CH];
    float x1A1[CH], s1A1[CH], x1B1[CH], s1B1[CH];

    // preload chunk 0 for both rows
#pragma unroll
    for (int j = 0; j < CH / 4; ++j) {
        *(float4*)&lpA0[4 * j] = *(const float4*)&Ar0[4 * j];
        *(float4*)&lqA0[4 * j] = *(const float4*)&Br0[4 * j];
        *(float4*)&lpA1[4 * j] = *(const float4*)&Ar1[4 * j];
        *(float4*)&lqA1[4 * j] = *(const float4*)&Br1[4 * j];
    }

    const int NCHUNK = NI / CH;  // 512 (even)
    for (int c = 0; c < NCHUNK; c += 2) {
        const int base0 = c * CH, base1 = (c + 1) * CH, base2 = (c + 2) * CH;

        // prefetch chunk c+1 into B buffers (both rows)
#pragma unroll
        for (int j = 0; j < CH / 4; ++j) {
            *(float4*)&lpB0[4 * j] = *(const float4*)&Ar0[base1 + 4 * j];
            *(float4*)&lqB0[4 * j] = *(const float4*)&Br0[base1 + 4 * j];
            *(float4*)&lpB1[4 * j] = *(const float4*)&Ar1[base1 + 4 * j];
            *(float4*)&lqB1[4 * j] = *(const float4*)&Br1[base1 + 4 * j];
        }

        // compute chunk c — two interleaved independent chains
#pragma unroll
        for (int j = 0; j < CH; ++j) {
            scan_step(lpA0[j], lqA0[j], S0a, S1a, x1A0[j], s1A0[j]);
            scan_step(lpA1[j], lqA1[j], S0b, S1b, x1A1[j], s1A1[j]);
        }
#pragma unroll
        for (int j = 0; j < CH / 4; ++j) {
            *(float4*)&Ar0[base0 + 4 * j] = *(float4*)&x1A0[4 * j];
            *(float4*)&Br0[base0 + 4 * j] = *(float4*)&s1A0[4 * j];
            *(float4*)&Ar1[base0 + 4 * j] = *(float4*)&x1A1[4 * j];
            *(float4*)&Br1[base0 + 4 * j] = *(float4*)&s1A1[4 * j];
        }

        // prefetch chunk c+2 into A buffers (both rows)
        if (c + 2 < NCHUNK) {
#pragma unroll
            for (int j = 0; j < CH / 4; ++j) {
                *(float4*)&lpA0[4 * j] = *(const float4*)&Ar0[base2 + 4 * j];
                *(float4*)&lqA0[4 * j] = *(const float4*)&Br0[base2 + 4 * j];
                *(float4*)&lpA1[4 * j] = *(const float4*)&Ar1[base2 + 4 * j];
                *(float4*)&lqA1[4 * j] = *(const float4*)&Br1[base2 + 4 * j];
            }
        }

        // compute chunk c+1 — two interleaved independent chains
#pragma unroll
        for (int j = 0; j < CH; ++j) {
            scan_step(lpB0[j], lqB0[j], S0a, S1a, x1B0[j], s1B0[j]);
            scan_step(lpB1[j], lqB1[j], S0b, S1b, x1B1[j], s1B1[j]);
        }
#pragma unroll
        for (int j = 0; j < CH / 4; ++j) {
            *(float4*)&Ar0[base1 + 4 * j] = *(float4*)&x1B0[4 * j];
            *(float4*)&Br0[base1 + 4 * j] = *(float4*)&s1B0[4 * j];
            *(float4*)&Ar1[base1 + 4 * j] = *(float4*)&x1B1[4 * j];
            *(float4*)&Br1[base1 + 4 * j] = *(float4*)&s1B1[4 * j];
        }
    }
}

// ---------------- Kernel 3: parallel decide + argmax + output write (precise, unchanged) --
__global__ __launch_bounds__(256) void decide_kernel(const float* __restrict__ A,  // x1
                                                     const float* __restrict__ S,  // S1 (aliases out)
                                                     const float* __restrict__ noise,
                                                     float* __restrict__ out) {
    int row = blockIdx.x;
    const float4* x1r = (const float4*)(A + (size_t)row * NI);
    const float4* s1r = (const float4*)(S + (size_t)row * NI);
    const float4* ur = (const float4*)(noise + (size_t)row * NI);
    float4* outr = (float4*)(out + (size_t)row * NI);
    int tid = threadIdx.x;

    int best = -1;
#pragma unroll
    for (int k = 0; k < NI / 4 / 256; ++k) {  // 8
        int g = tid + k * 256;
        float4 x1 = x1r[g];
        float4 s1 = s1r[g];
        float4 u = ur[g];
#pragma unroll
        for (int j = 0; j < 4; ++j) {
            float p = fminf((&x1.x)[j] - (&s1.x)[j], 0.0f);
            float q = log1mexp_f(p);            // p==0 -> -inf -> prob 1
            float z = p - q;
            float prob = 1.0f / (1.0f + expf(-z));
            if ((&u.x)[j] < prob) {
                int i = 4 * g + j;
                best = (i > best) ? i : best;
            }
        }
    }

#pragma unroll
    for (int off = 32; off > 0; off >>= 1) {
        int o = __shfl_down(best, off);
        best = (o > best) ? o : best;
    }
    __shared__ int lds[4];
    __shared__ int sel_s;
    int wid = tid >> 6;
    if ((tid & 63) == 0) lds[wid] = best;
    __syncthreads();
    if (tid == 0) {
        int s01 = (lds[0] > lds[1]) ? lds[0] : lds[1];
        int s23 = (lds[2] > lds[3]) ? lds[2] : lds[3];
        sel_s = (s01 > s23) ? s01 : s23;
    }
    __syncthreads();
    int sel = sel_s;

#pragma unroll
    for (int k = 0; k < NI / 4 / 256; ++k) {
        int g = tid + k * 256;
        int i0 = 4 * g;
        float4 v;
        v.x = (i0 == sel) ? 1.0f : 0.0f;
        v.y = (i0 + 1 == sel) ? 1.0f : 0.0f;
        v.z = (i0 + 2 == sel) ? 1.0f : 0.0f;
        v.w = (i0 + 3 == sel) ? 1.0f : 0.0f;
        outr[g] = v;
    }
}

extern "C" void kernel_launch(void* const* d_in, const int* in_sizes, int n_in,
                              void* d_out, int out_size, void* d_ws, size_t ws_size,
                              hipStream_t stream) {
    (void)in_sizes; (void)n_in; (void)out_size; (void)ws_size;
    const float* logits = (const float*)d_in[0];
    const float* noise = (const float*)d_in[1];
    float* out = (float*)d_out;       // lq -> S1 -> final 0/1 output (16 MB)
    float* A = (float*)d_ws;          // lp -> x1 (16 MB of ws)

    int total4 = NB * NI / 4;
    prep_kernel<<<total4 / 256, 256, 0, stream>>>(logits, A, out);
    scan_kernel<<<4, 64, 0, stream>>>(A, out);  // 256 lanes x 2 rows
    decide_kernel<<<NB, 256, 0, stream>>>(A, out, noise, out);
}

// Round 3
// 408.191 us; speedup vs baseline: 2.1723x; 2.1723x over previous
//
#include <hip/hip_runtime.h>
#include <math.h>

#define NB 512
#define NI 8192
#define NG (NI / 4)   // 2048 float4 item-groups per row
#define NLOG2 0.69314718055994530942f

__device__ __forceinline__ float log1mexp_f(float x) {
    // log(1 - exp(x)) for x <= 0, matching reference branch structure (precise ocml)
    return (x > -NLOG2) ? logf(-expm1f(x)) : log1pf(-expf(x));
}

__device__ int g_sel[NB];  // per-row selected index (decide_pick -> writeout)

// ---------------- Kernel 1: prep + pack-transpose ----------------
// Same lp/lq math as the verified kernel; output layout is PACKED-TRANSPOSED:
// float4 index (g*NB + b) holds items 4g..4g+3 of row b. This makes the scan's
// wave64 accesses fully coalesced (64 consecutive float4s = 1KB/instr).
// LDS tile transpose keeps prep's reads AND writes coalesced.
#define TB 64   // rows per tile
#define TK 16   // float4-groups per tile (64 items)
__global__ __launch_bounds__(256) void prep_kernel(const float* __restrict__ logits,
                                                   float* __restrict__ Alp,   // ws: lp_p (later x1_p)
                                                   float* __restrict__ Blq) { // out: lq_p (later s1_p)
    __shared__ float4 lp_t[TB][TK + 1];  // +1 pad: write-phase read stride 17*16B -> ~2-way (free)
    __shared__ float4 lq_t[TB][TK + 1];
    int bx = blockIdx.x;
    int tb = (bx & 7) * TB;        // row-tile base (512/64 = 8 tiles)
    int tkb = (bx >> 3) * TK;      // group-tile base (2048/16 = 128 tiles)
    int t = threadIdx.x;

    // read phase: coalesced logits reads, compute lp/lq (exact original math)
    int kl = t & 15;
    int rl0 = t >> 4;  // 0..15
#pragma unroll
    for (int r = 0; r < 4; ++r) {
        int row_local = r * 16 + rl0;
        float4 x4 = *(const float4*)&logits[(size_t)(tb + row_local) * NI + (size_t)(tkb + kl) * 4];
        float4 lp4, lq4;
        const float* xs = &x4.x;
        float* lps = &lp4.x;
        float* lqs = &lq4.x;
#pragma unroll
        for (int j = 0; j < 4; ++j) {
            float x = xs[j];
            float lp = -(fmaxf(-x, 0.0f) + log1pf(expf(-fabsf(x))));
            lp = fminf(lp, -1e-7f);
            lps[j] = lp;
            lqs[j] = log1mexp_f(lp);
        }
        lp_t[row_local][kl] = lp4;
        lq_t[row_local][kl] = lq4;
    }
    __syncthreads();

    // write phase: coalesced packed writes (64 consecutive rows per group)
    int bl = t & 63;
    int kw0 = t >> 6;  // 0..3
#pragma unroll
    for (int w = 0; w < 4; ++w) {
        int k_local = w * 4 + kw0;
        size_t dst = (size_t)(tkb + k_local) * NB + (size_t)(tb + bl);
        ((float4*)Alp)[dst] = lp_t[bl][k_local];
        ((float4*)Blq)[dst] = lq_t[bl][k_local];
    }
}

// ---------------- Kernel 2: sequential per-row scan (coalesced packed layout) ----------
// 1 row/lane, 8 blocks x 64 lanes (Round-2 showed 2-row ILP is worthless: the scan was
// memory-pipe-bound on uncoalesced accesses, not chain-latency-bound). With the packed
// layout each wave load/store is one contiguous 1KB segment. Per-row fp op order is
// bit-identical to the verified kernel.
__device__ __forceinline__ void scan_step(float lp, float lq, float& S0, float& S1,
                                          float& x1o, float& s1o) {
    const float L2E = 1.44269504088896340736f;   // log2(e)
    const float LN2 = 0.69314718055994530942f;   // ln(2)
    float x1 = S0 + lp;
    float x2 = S1 + lq;
    float d  = x1 - x2;                          // never NaN (x1 finite)
    float m  = fmaxf(x1, x2);
    float z  = fabsf(d) * -L2E;                  // single VOP3 mul w/ -abs modifier
    float e  = __builtin_amdgcn_exp2f(z);        // v_exp_f32; exp2(-inf)=0 handles S1=-inf start
    float a  = 1.0f + e;
    float l  = __builtin_amdgcn_logf(a);         // v_log_f32 = log2
    S1 = fmaf(l, LN2, m);                        // m + softplus(-|d|), single rounding
    S0 = S0 + lq;
    x1o = x1;
    s1o = S1;
}

__device__ __forceinline__ void scan_step4(float4 lp, float4 lq, float& S0, float& S1,
                                           float4& x1v, float4& s1v) {
    scan_step(lp.x, lq.x, S0, S1, x1v.x, s1v.x);
    scan_step(lp.y, lq.y, S0, S1, x1v.y, s1v.y);
    scan_step(lp.z, lq.z, S0, S1, x1v.z, s1v.z);
    scan_step(lp.w, lq.w, S0, S1, x1v.w, s1v.w);
}

#define SD 8  // float4-groups per chunk (32 items); lookahead slack ~ 32 steps of compute
__global__ __launch_bounds__(64, 1) void scan_kernel(float* __restrict__ A,
                                                     float* __restrict__ B) {
    int row = blockIdx.x * 64 + threadIdx.x;  // 8 blocks x 64 lanes = 512 rows
    float4* Ap = (float4*)A;  // float4 index: g*NB + row
    float4* Bp = (float4*)B;

    float S0 = 0.0f;
    float S1 = -INFINITY;

    float4 lpA[SD], lqA[SD], lpB[SD], lqB[SD];

    // preload chunk 0
#pragma unroll
    for (int j = 0; j < SD; ++j) {
        lpA[j] = Ap[(size_t)j * NB + row];
        lqA[j] = Bp[(size_t)j * NB + row];
    }

    const int NCHUNK = NG / SD;  // 256 (even)
    for (int c = 0; c < NCHUNK; c += 2) {
        size_t g1 = (size_t)(c + 1) * SD;
        size_t g2 = (size_t)(c + 2) * SD;

        // prefetch chunk c+1 into B buffers
#pragma unroll
        for (int j = 0; j < SD; ++j) {
            lpB[j] = Ap[(g1 + j) * NB + row];
            lqB[j] = Bp[(g1 + j) * NB + row];
        }

        // compute + store chunk c (stores hit provably-distinct addresses -> no forced drain)
#pragma unroll
        for (int j = 0; j < SD; ++j) {
            float4 x1v, s1v;
            scan_step4(lpA[j], lqA[j], S0, S1, x1v, s1v);
            size_t g = (size_t)c * SD + j;
            Ap[g * NB + row] = x1v;
            Bp[g * NB + row] = s1v;
        }

        // prefetch chunk c+2 into A buffers
        if (c + 2 < NCHUNK) {
#pragma unroll
            for (int j = 0; j < SD; ++j) {
                lpA[j] = Ap[(g2 + j) * NB + row];
                lqA[j] = Bp[(g2 + j) * NB + row];
            }
        }

        // compute + store chunk c+1
#pragma unroll
        for (int j = 0; j < SD; ++j) {
            float4 x1v, s1v;
            scan_step4(lpB[j], lqB[j], S0, S1, x1v, s1v);
            size_t g = g1 + j;
            Ap[g * NB + row] = x1v;
            Bp[g * NB + row] = s1v;
        }
    }
}

// ---------------- Kernel 3: decide (reads packed x1/s1) -> per-row selected index -------
// s1 is scattered across the whole `out` buffer in packed layout, so the one-hot write
// must move to a separate kernel (kernel-boundary ordering kills the inter-block race).
__global__ __launch_bounds__(256) void decide_kernel(const float* __restrict__ A,  // x1_p
                                                     const float* __restrict__ S,  // s1_p
                                                     const float* __restrict__ noise) {
    int row = blockIdx.x;
    const float4* x1p = (const float4*)A;
    const float4* s1p = (const float4*)S;
    const float4* ur = (const float4*)(noise + (size_t)row * NI);
    int tid = threadIdx.x;

    int best = -1;
#pragma unroll
    for (int k = 0; k < NG / 256; ++k) {  // 8
        int g = tid + k * 256;
        float4 x1 = x1p[(size_t)g * NB + row];
        float4 s1 = s1p[(size_t)g * NB + row];
        float4 u = ur[g];
#pragma unroll
        for (int j = 0; j < 4; ++j) {
            float p = fminf((&x1.x)[j] - (&s1.x)[j], 0.0f);
            float q = log1mexp_f(p);            // p==0 -> -inf -> prob 1
            float z = p - q;
            float prob = 1.0f / (1.0f + expf(-z));
            if ((&u.x)[j] < prob) {
                int i = 4 * g + j;
                best = (i > best) ? i : best;
            }
        }
    }

#pragma unroll
    for (int off = 32; off > 0; off >>= 1) {
        int o = __shfl_down(best, off);
        best = (o > best) ? o : best;
    }
    __shared__ int lds[4];
    int wid = tid >> 6;
    if ((tid & 63) == 0) lds[wid] = best;
    __syncthreads();
    if (tid == 0) {
        int s01 = (lds[0] > lds[1]) ? lds[0] : lds[1];
        int s23 = (lds[2] > lds[3]) ? lds[2] : lds[3];
        g_sel[row] = (s01 > s23) ? s01 : s23;
    }
}

// ---------------- Kernel 4: one-hot output write (row-major) ----------------
__global__ __launch_bounds__(256) void writeout_kernel(float* __restrict__ out) {
    int row = blockIdx.x;
    int sel = g_sel[row];
    float4* outr = (float4*)(out + (size_t)row * NI);
    int tid = threadIdx.x;
#pragma unroll
    for (int k = 0; k < NG / 256; ++k) {
        int g = tid + k * 256;
        int i0 = 4 * g;
        float4 v;
        v.x = (i0 == sel) ? 1.0f : 0.0f;
        v.y = (i0 + 1 == sel) ? 1.0f : 0.0f;
        v.z = (i0 + 2 == sel) ? 1.0f : 0.0f;
        v.w = (i0 + 3 == sel) ? 1.0f : 0.0f;
        outr[g] = v;
    }
}

extern "C" void kernel_launch(void* const* d_in, const int* in_sizes, int n_in,
                              void* d_out, int out_size, void* d_ws, size_t ws_size,
                              hipStream_t stream) {
    (void)in_sizes; (void)n_in; (void)out_size; (void)ws_size;
    const float* logits = (const float*)d_in[0];
    const float* noise = (const float*)d_in[1];
    float* out = (float*)d_out;       // lq_p -> s1_p -> final 0/1 output (16 MB)
    float* A = (float*)d_ws;          // lp_p -> x1_p (16 MB of ws)

    prep_kernel<<<8 * (NG / TK), 256, 0, stream>>>(logits, A, out);  // 1024 blocks
    scan_kernel<<<8, 64, 0, stream>>>(A, out);
    decide_kernel<<<NB, 256, 0, stream>>>(A, out, noise);
    writeout_kernel<<<NB, 256, 0, stream>>>(out);
}